// Round 12
// baseline (117.017 us; speedup 1.0000x reference)
//
#include <hip/hip_runtime.h>

#define NTOK 32768
#define CDIM 256
#define KCODE 1024
#define C4 64   // CDIM/4

typedef __bf16 bf16x8 __attribute__((ext_vector_type(8)));
typedef float  f32x4  __attribute__((ext_vector_type(4)));
typedef const __attribute__((address_space(1))) void* as1cvp;
typedef __attribute__((address_space(3))) void* as3vp;

// ---------------- K1: fused prep --------------------------------------------
// blocks [0,1024): transpose+normalize z -> znt fp32 + znt2
// blocks [1024,1040): normalize codebook -> en fp32, en2, eh/el bf16
__global__ void k_prep(const float* __restrict__ z, const float* __restrict__ emb,
                       float* __restrict__ znt, float* __restrict__ znt2,
                       float* __restrict__ en, float* __restrict__ en2,
                       __bf16* __restrict__ eh, __bf16* __restrict__ el) {
    __shared__ float zsb[CDIM * 32];   // 32 KB, [c][ (tok+c)&31 ]
    __shared__ float ssp[256];
    __shared__ float dens[32];
    int tid = threadIdx.x;

    if (blockIdx.x >= 1024) {
        // ---- codebook part: 64 codes/block, 4 threads/code
        int k = (blockIdx.x - 1024) * 64 + (tid >> 2);
        int q = tid & 3;
        const float4* ep = reinterpret_cast<const float4*>(emb) + (size_t)k * C4 + q * 16;
        float4 v[16];
        float ss = 0.f;
        #pragma unroll
        for (int i = 0; i < 16; ++i) {
            v[i] = ep[i];
            ss += v[i].x*v[i].x + v[i].y*v[i].y + v[i].z*v[i].z + v[i].w*v[i].w;
        }
        ss += __shfl_xor(ss, 1, 4); ss += __shfl_xor(ss, 2, 4);
        float den = fmaxf(sqrtf(ss), 1e-12f);
        float s2 = 0.f;
        float4* enp = reinterpret_cast<float4*>(en) + (size_t)k * C4 + q * 16;
        __bf16* ehp = eh + (size_t)k * CDIM + q * 64;
        __bf16* elp = el + (size_t)k * CDIM + q * 64;
        #pragma unroll
        for (int i = 0; i < 16; ++i) {
            float e4[4] = {v[i].x / den, v[i].y / den, v[i].z / den, v[i].w / den};
            enp[i] = make_float4(e4[0], e4[1], e4[2], e4[3]);
            #pragma unroll
            for (int j = 0; j < 4; ++j) {
                s2 += e4[j] * e4[j];
                __bf16 h = (__bf16)e4[j];
                ehp[i * 4 + j] = h;
                elp[i * 4 + j] = (__bf16)(e4[j] - (float)h);
            }
        }
        s2 += __shfl_xor(s2, 1, 4); s2 += __shfl_xor(s2, 2, 4);
        if (q == 0) en2[k] = s2;
        return;
    }

    // ---- z part: 32 tokens/block
    int t0  = blockIdx.x * 32;
    int n   = t0 >> 10;
    int thw0 = t0 & 1023;

    int l = tid & 31, grp = tid >> 5;          // 8 c-stripes
    const float* zb = z + (((size_t)(n * CDIM)) << 10) + thw0 + l;
    float ss = 0.f;
    int c0 = grp * 32;
    for (int cc = 0; cc < 32; ++cc) {
        int c = c0 + cc;
        float v = zb[((size_t)c) << 10];
        zsb[c * 32 + ((l + c) & 31)] = v;
        ss += v * v;
    }
    ssp[tid] = ss;
    __syncthreads();
    if (tid < 32) {
        float tot = 0.f;
        #pragma unroll
        for (int g = 0; g < 8; ++g) tot += ssp[g * 32 + tid];
        dens[tid] = fmaxf(sqrtf(tot), 1e-12f);
    }
    __syncthreads();

    int l2 = tid & 63, tg = tid >> 6;          // 4 token-groups of 8
    for (int it = 0; it < 8; ++it) {
        int tok = tg * 8 + it;
        float den = dens[tok];
        float s2 = 0.f;
        #pragma unroll
        for (int cq = 0; cq < 4; ++cq) {
            int c = cq * 64 + l2;
            float v = zsb[c * 32 + ((tok + c) & 31)] / den;
            znt[((size_t)(t0 + tok)) * CDIM + c] = v;
            s2 += v * v;
        }
        #pragma unroll
        for (int o = 32; o >= 1; o >>= 1) s2 += __shfl_xor(s2, o, 64);
        if (l2 == 0) znt2[t0 + tok] = s2;
    }
}

// ---------------- K2: MFMA GEMM + top-2 + fused fixup + fused gather --------
// 512 blocks x 256 threads (4 waves: 2M x 2N) — r5/r8 proven main loop.
// A read from fp32 znt once, split hi/lo in regs. B (eh/el) double-buffered
// in LDS via global_load_lds with pre-swizzled source. Float top-2 (32-bit
// compares). Epilogue: merge -> fp32 fixup -> bank-safe LDS gather -> NCHW.
__global__ __launch_bounds__(256, 2) void k_mfma(
        const float* __restrict__ znt,
        const __bf16* __restrict__ eh, const __bf16* __restrict__ el,
        const float* __restrict__ en2g,
        const float* __restrict__ znt2, const float* __restrict__ en,
        const float* __restrict__ emb, float* __restrict__ out) {
    // union: [0,65536) ebuf | [65536,69632) en2s ; gather reuses [0,65792) as qt[64][257]
    __shared__ __align__(16) char smem_u[69632];
    __shared__ uint4 t2l[64][2];
    __shared__ int idxs[64];
    __bf16* ebuf = reinterpret_cast<__bf16*>(smem_u);            // [2][2][8192]
    float*  en2s = reinterpret_cast<float*>(smem_u + 65536);     // [1024]
    float*  qt   = reinterpret_cast<float*>(smem_u);             // [64][257]

    int tid = threadIdx.x;
    int l = tid & 63, wid = tid >> 6;
    int mw = wid >> 1, nw = wid & 1;           // 2M x 2N
    int t0 = blockIdx.x * 64;
    int row = l & 15, kg = l >> 4;             // frag row / k-group

    for (int i = tid; i < KCODE; i += 256) en2s[i] = en2g[i];

    // hoist A from fp32 znt, split hi/lo: 2 mt x 8 ks x {h,l} = 128 VGPR
    bf16x8 ah[2][8], al_[2][8];
    #pragma unroll
    for (int mt = 0; mt < 2; ++mt) {
        size_t tok = (size_t)(t0 + mw * 32 + mt * 16 + row);
        const float* pz = znt + tok * CDIM + kg * 8;
        #pragma unroll
        for (int ks = 0; ks < 8; ++ks) {
            float f[8];
            *reinterpret_cast<float4*>(&f[0]) = *reinterpret_cast<const float4*>(pz + ks * 32);
            *reinterpret_cast<float4*>(&f[4]) = *reinterpret_cast<const float4*>(pz + ks * 32 + 4);
            bf16x8 h, lo;
            #pragma unroll
            for (int q = 0; q < 8; ++q) {
                __bf16 hv = (__bf16)f[q];
                h[q] = hv;
                lo[q] = (__bf16)(f[q] - (float)hv);
            }
            ah[mt][ks] = h; al_[mt][ks] = lo;
        }
    }

    // float top-2 per lane: 2 mtiles x 4 rows
    float v1f[8], v2f[8]; int i1a[8], i2a[8];
    #pragma unroll
    for (int i = 0; i < 8; ++i) { v1f[i] = 3.4e38f; v2f[i] = 3.4e38f; i1a[i] = 0; i2a[i] = 0; }

    // stage one 32-code chunk (hi+lo) with XOR swizzle (slot = c16 ^ (code&15))
    auto stage = [&](int buf, int ch) {
        #pragma unroll
        for (int a = 0; a < 2; ++a) {
            const __bf16* src = a ? el : eh;
            #pragma unroll
            for (int i2 = 0; i2 < 4; ++i2) {
                int s = i2 * 256 + tid;
                int code = s >> 5, c16 = s & 31;
                int gslot = c16 ^ (code & 15);
                const __bf16* gp = src + ((size_t)(ch * 32 + code)) * CDIM + gslot * 8;
                __bf16* ld = ebuf + (size_t)(buf * 2 + a) * 8192 + (size_t)(i2 * 256 + wid * 64) * 8;
                __builtin_amdgcn_global_load_lds((as1cvp)gp, (as3vp)ld, 16, 0, 0);
            }
        }
    };

    stage(0, 0);
    __syncthreads();
    #pragma unroll 2
    for (int ch = 0; ch < 32; ++ch) {
        int cur = ch & 1;
        if (ch < 31) stage(cur ^ 1, ch + 1);

        const __bf16* bh_base = ebuf + (size_t)(cur * 2 + 0) * 8192;
        const __bf16* bl_base = ebuf + (size_t)(cur * 2 + 1) * 8192;

        f32x4 a0[2], a1[2], a2[2];
        #pragma unroll
        for (int mt = 0; mt < 2; ++mt)
            #pragma unroll
            for (int r = 0; r < 4; ++r) { a0[mt][r] = 0.f; a1[mt][r] = 0.f; a2[mt][r] = 0.f; }

        int code_l = nw * 16 + row;
        #pragma unroll
        for (int ks = 0; ks < 8; ++ks) {
            int slot = (ks * 4 + kg) ^ row;
            bf16x8 bh = *reinterpret_cast<const bf16x8*>(bh_base + code_l * 256 + slot * 8);
            bf16x8 bl = *reinterpret_cast<const bf16x8*>(bl_base + code_l * 256 + slot * 8);
            #pragma unroll
            for (int mt = 0; mt < 2; ++mt) {
                a0[mt] = __builtin_amdgcn_mfma_f32_16x16x32_bf16(ah[mt][ks],  bh, a0[mt], 0, 0, 0);
                a1[mt] = __builtin_amdgcn_mfma_f32_16x16x32_bf16(ah[mt][ks],  bl, a1[mt], 0, 0, 0);
                a2[mt] = __builtin_amdgcn_mfma_f32_16x16x32_bf16(al_[mt][ks], bh, a2[mt], 0, 0, 0);
            }
        }

        // selection: d' = e2 - 2*dot; float top-2, strict < keeps first index
        int code = ch * 32 + code_l;
        float e2v = en2s[code];
        #pragma unroll
        for (int mt = 0; mt < 2; ++mt)
            #pragma unroll
            for (int r = 0; r < 4; ++r) {
                float d = fmaf(-2.0f, (a0[mt][r] + a1[mt][r]) + a2[mt][r], e2v);
                int idx = mt * 4 + r;
                bool lt2 = d < v2f[idx];
                bool lt1 = d < v1f[idx];
                if (lt2) {
                    v2f[idx] = lt1 ? v1f[idx] : d;
                    i2a[idx] = lt1 ? i1a[idx] : code;
                    if (lt1) { v1f[idx] = d; i1a[idx] = code; }
                }
            }
        __syncthreads();
    }

    // butterfly top-2 merge across the 16 code-col lanes (lexicographic)
    #pragma unroll
    for (int i = 0; i < 8; ++i) {
        #pragma unroll
        for (int off = 1; off < 16; off <<= 1) {
            float ov1 = __shfl_xor(v1f[i], off, 16); int oi1 = __shfl_xor(i1a[i], off, 16);
            float ov2 = __shfl_xor(v2f[i], off, 16); int oi2 = __shfl_xor(i2a[i], off, 16);
            bool w = (ov1 < v1f[i]) || (ov1 == v1f[i] && oi1 < i1a[i]);  // other wins
            float lv = w ? v1f[i] : ov1; int li = w ? i1a[i] : oi1;      // loser of tops
            float s2v = w ? ov2 : v2f[i]; int s2i = w ? oi2 : i2a[i];    // winner's 2nd
            v1f[i] = w ? ov1 : v1f[i]; i1a[i] = w ? oi1 : i1a[i];
            bool s = (lv < s2v) || (lv == s2v && li < s2i);
            v2f[i] = s ? lv : s2v; i2a[i] = s ? li : s2i;
        }
    }
    if ((l & 15) == 0) {
        #pragma unroll
        for (int mt = 0; mt < 2; ++mt)
            #pragma unroll
            for (int r = 0; r < 4; ++r) {
                int tl = mw * 32 + mt * 16 + kg * 4 + r;   // C/D row mapping
                int i = mt * 4 + r;
                t2l[tl][nw] = make_uint4(__float_as_uint(v1f[i]), (unsigned)i1a[i],
                                         __float_as_uint(v2f[i]), (unsigned)i2a[i]);
            }
    }
    __syncthreads();

    // fused fp32 fixup: 4 threads per token, 64 dims each
    {
        int tl = tid >> 2, q = tid & 3;
        int t = t0 + tl;
        uint4 A = t2l[tl][0], B = t2l[tl][1];
        float av1 = __uint_as_float(A.x); int ai1 = (int)A.y;
        float av2 = __uint_as_float(A.z); int ai2 = (int)A.w;
        float bv1 = __uint_as_float(B.x); int bi1 = (int)B.y;
        float bv2 = __uint_as_float(B.z); int bi2 = (int)B.w;
        bool w = (bv1 < av1) || (bv1 == av1 && bi1 < ai1);
        int   c1 = w ? bi1 : ai1;
        float lv = w ? av1 : bv1; int li = w ? ai1 : bi1;
        float wv2 = w ? bv2 : av2; int wi2 = w ? bi2 : ai2;
        bool s = (lv < wv2) || (lv == wv2 && li < wi2);
        int   c2 = s ? li : wi2;

        const float4* zp  = reinterpret_cast<const float4*>(znt) + (size_t)t  * C4 + q * 16;
        const float4* eap = reinterpret_cast<const float4*>(en)  + (size_t)c1 * C4 + q * 16;
        const float4* ebp = reinterpret_cast<const float4*>(en)  + (size_t)c2 * C4 + q * 16;
        float da = 0.f, db = 0.f;
        #pragma unroll
        for (int i = 0; i < 16; ++i) {
            float4 zv = zp[i], av = eap[i], bv = ebp[i];
            da += zv.x*av.x + zv.y*av.y + zv.z*av.z + zv.w*av.w;
            db += zv.x*bv.x + zv.y*bv.y + zv.z*bv.z + zv.w*bv.w;
        }
        da += __shfl_xor(da, 1, 4); da += __shfl_xor(da, 2, 4);
        db += __shfl_xor(db, 1, 4); db += __shfl_xor(db, 2, 4);
        if (q == 0) {
            float z2 = znt2[t];
            float d1 = (z2 + en2s[c1]) - 2.0f * da;
            float d2 = (z2 + en2s[c2]) - 2.0f * db;
            int k = (d2 < d1 || (d2 == d1 && c2 < c1)) ? c2 : c1;
            idxs[tl] = k;
            out[(size_t)NTOK * CDIM + t] = (float)k;   // index output tail
        }
    }
    __syncthreads();   // en2s reads done; idxs visible; qt may overwrite

    // gather stage: emb rows -> qt[64][257]; tl varies fastest (bank-safe)
    {
        int tl = tid & 63, q = tid >> 6;       // 4 c-segments of 64 floats
        int kidx = idxs[tl];
        const float4* ep = reinterpret_cast<const float4*>(emb + (size_t)kidx * CDIM + q * 64);
        #pragma unroll
        for (int i = 0; i < 16; ++i) {
            float4 v = ep[i];
            int cb = q * 64 + i * 4;
            qt[tl * 257 + cb + 0] = v.x;
            qt[tl * 257 + cb + 1] = v.y;
            qt[tl * 257 + cb + 2] = v.z;
            qt[tl * 257 + cb + 3] = v.w;
        }
    }
    __syncthreads();

    // transpose write: lanes = hw (coalesced 256B stores), NCHW
    {
        int hwo = tid & 63, cg = tid >> 6;     // 4 c-groups of 64
        int n = t0 >> 10, hw = (t0 & 1023) + hwo;
        float* ob = out + (size_t)n * (CDIM * 1024) + hw;
        #pragma unroll 8
        for (int cc = 0; cc < 64; ++cc) {
            int c = cg * 64 + cc;
            ob[(size_t)c * 1024] = qt[hwo * 257 + c];
        }
    }
}

extern "C" void kernel_launch(void* const* d_in, const int* in_sizes, int n_in,
                              void* d_out, int out_size, void* d_ws, size_t ws_size,
                              hipStream_t stream) {
    const float* z   = (const float*)d_in[0];
    const float* emb = (const float*)d_in[1];
    float* out  = (float*)d_out;

    float*  en   = (float*)d_ws;                        // 1 MB
    float*  en2  = en + (size_t)KCODE * CDIM;           // 4 KB
    float*  znt2 = en2 + KCODE;                         // 128 KB
    __bf16* eh   = (__bf16*)(znt2 + NTOK);              // 512 KB
    __bf16* el   = eh + (size_t)KCODE * CDIM;           // 512 KB
    float*  znt  = (float*)(el + (size_t)KCODE * CDIM); // 32 MB

    k_prep<<<1024 + 16, 256, 0, stream>>>(z, emb, znt, znt2, en, en2, eh, el);
    k_mfma<<<NTOK / 64, 256, 0, stream>>>(znt, eh, el, en2, znt2, en, emb, out);
}

// Round 13
// 102.064 us; speedup vs baseline: 1.1465x; 1.1465x over previous
//
#include <hip/hip_runtime.h>

#define NTOK 32768
#define CDIM 256
#define KCODE 1024
#define C4 64   // CDIM/4

typedef __bf16 bf16x8 __attribute__((ext_vector_type(8)));
typedef float  f32x4  __attribute__((ext_vector_type(4)));
typedef const __attribute__((address_space(1))) void* as1cvp;
typedef __attribute__((address_space(3))) void* as3vp;

__device__ __forceinline__ unsigned long long umin64(unsigned long long a, unsigned long long b) { return a < b ? a : b; }
__device__ __forceinline__ unsigned long long umax64(unsigned long long a, unsigned long long b) { return a > b ? a : b; }

// ---------------- K1: fused prep --------------------------------------------
// blocks [0,1024): transpose+normalize z -> znt fp32 + znt2
// blocks [1024,1040): normalize codebook -> en fp32, en2, eh/el bf16
__global__ void k_prep(const float* __restrict__ z, const float* __restrict__ emb,
                       float* __restrict__ znt, float* __restrict__ znt2,
                       float* __restrict__ en, float* __restrict__ en2,
                       __bf16* __restrict__ eh, __bf16* __restrict__ el) {
    __shared__ float zsb[CDIM * 32];   // 32 KB, [c][ (tok+c)&31 ]
    __shared__ float ssp[256];
    __shared__ float dens[32];
    int tid = threadIdx.x;

    if (blockIdx.x >= 1024) {
        // ---- codebook part: 64 codes/block, 4 threads/code
        int k = (blockIdx.x - 1024) * 64 + (tid >> 2);
        int q = tid & 3;
        const float4* ep = reinterpret_cast<const float4*>(emb) + (size_t)k * C4 + q * 16;
        float4 v[16];
        float ss = 0.f;
        #pragma unroll
        for (int i = 0; i < 16; ++i) {
            v[i] = ep[i];
            ss += v[i].x*v[i].x + v[i].y*v[i].y + v[i].z*v[i].z + v[i].w*v[i].w;
        }
        ss += __shfl_xor(ss, 1, 4); ss += __shfl_xor(ss, 2, 4);
        float den = fmaxf(sqrtf(ss), 1e-12f);
        float s2 = 0.f;
        float4* enp = reinterpret_cast<float4*>(en) + (size_t)k * C4 + q * 16;
        __bf16* ehp = eh + (size_t)k * CDIM + q * 64;
        __bf16* elp = el + (size_t)k * CDIM + q * 64;
        #pragma unroll
        for (int i = 0; i < 16; ++i) {
            float e4[4] = {v[i].x / den, v[i].y / den, v[i].z / den, v[i].w / den};
            enp[i] = make_float4(e4[0], e4[1], e4[2], e4[3]);
            #pragma unroll
            for (int j = 0; j < 4; ++j) {
                s2 += e4[j] * e4[j];
                __bf16 h = (__bf16)e4[j];
                ehp[i * 4 + j] = h;
                elp[i * 4 + j] = (__bf16)(e4[j] - (float)h);
            }
        }
        s2 += __shfl_xor(s2, 1, 4); s2 += __shfl_xor(s2, 2, 4);
        if (q == 0) en2[k] = s2;
        return;
    }

    // ---- z part: 32 tokens/block
    int t0  = blockIdx.x * 32;
    int n   = t0 >> 10;
    int thw0 = t0 & 1023;

    int l = tid & 31, grp = tid >> 5;          // 8 c-stripes
    const float* zb = z + (((size_t)(n * CDIM)) << 10) + thw0 + l;
    float ss = 0.f;
    int c0 = grp * 32;
    for (int cc = 0; cc < 32; ++cc) {
        int c = c0 + cc;
        float v = zb[((size_t)c) << 10];
        zsb[c * 32 + ((l + c) & 31)] = v;
        ss += v * v;
    }
    ssp[tid] = ss;
    __syncthreads();
    if (tid < 32) {
        float tot = 0.f;
        #pragma unroll
        for (int g = 0; g < 8; ++g) tot += ssp[g * 32 + tid];
        dens[tid] = fmaxf(sqrtf(tot), 1e-12f);
    }
    __syncthreads();

    int l2 = tid & 63, tg = tid >> 6;          // 4 token-groups of 8
    for (int it = 0; it < 8; ++it) {
        int tok = tg * 8 + it;
        float den = dens[tok];
        float s2 = 0.f;
        #pragma unroll
        for (int cq = 0; cq < 4; ++cq) {
            int c = cq * 64 + l2;
            float v = zsb[c * 32 + ((tok + c) & 31)] / den;
            znt[((size_t)(t0 + tok)) * CDIM + c] = v;
            s2 += v * v;
        }
        #pragma unroll
        for (int o = 32; o >= 1; o >>= 1) s2 += __shfl_xor(s2, o, 64);
        if (l2 == 0) znt2[t0 + tok] = s2;
    }
}

// ---------------- K2: MFMA GEMM + top-2 + fused fixup + fused gather --------
// 512 blocks x 256 threads (4 waves: 2M x 2N) — r8's proven main loop (u64
// sortable-key top-2). A read from fp32 znt once, split hi/lo in regs. B
// (eh/el) double-buffered in LDS via global_load_lds with pre-swizzled
// source. Epilogue: u64 merge -> fp32 fixup -> bank-safe gather -> NCHW.
__global__ __launch_bounds__(256, 2) void k_mfma(
        const float* __restrict__ znt,
        const __bf16* __restrict__ eh, const __bf16* __restrict__ el,
        const float* __restrict__ en2g,
        const float* __restrict__ znt2, const float* __restrict__ en,
        const float* __restrict__ emb, float* __restrict__ out) {
    // union: [0,65536) ebuf | [65536,69632) en2s ; gather reuses [0,65792) as qt[64][257]
    __shared__ __align__(16) char smem_u[69632];
    __shared__ unsigned long long t2l[64][2][2];
    __shared__ int idxs[64];
    __bf16* ebuf = reinterpret_cast<__bf16*>(smem_u);            // [2][2][8192]
    float*  en2s = reinterpret_cast<float*>(smem_u + 65536);     // [1024]
    float*  qt   = reinterpret_cast<float*>(smem_u);             // [64][257]

    int tid = threadIdx.x;
    int l = tid & 63, wid = tid >> 6;
    int mw = wid >> 1, nw = wid & 1;           // 2M x 2N
    int t0 = blockIdx.x * 64;
    int row = l & 15, kg = l >> 4;             // frag row / k-group

    for (int i = tid; i < KCODE; i += 256) en2s[i] = en2g[i];

    // hoist A from fp32 znt, split hi/lo: 2 mt x 8 ks x {h,l} = 128 VGPR
    bf16x8 ah[2][8], al_[2][8];
    #pragma unroll
    for (int mt = 0; mt < 2; ++mt) {
        size_t tok = (size_t)(t0 + mw * 32 + mt * 16 + row);
        const float* pz = znt + tok * CDIM + kg * 8;
        #pragma unroll
        for (int ks = 0; ks < 8; ++ks) {
            float f[8];
            *reinterpret_cast<float4*>(&f[0]) = *reinterpret_cast<const float4*>(pz + ks * 32);
            *reinterpret_cast<float4*>(&f[4]) = *reinterpret_cast<const float4*>(pz + ks * 32 + 4);
            bf16x8 h, lo;
            #pragma unroll
            for (int q = 0; q < 8; ++q) {
                __bf16 hv = (__bf16)f[q];
                h[q] = hv;
                lo[q] = (__bf16)(f[q] - (float)hv);
            }
            ah[mt][ks] = h; al_[mt][ks] = lo;
        }
    }

    // top-2 u64 keys per lane: 2 mtiles x 4 rows
    unsigned long long b1[8], b2[8];
    #pragma unroll
    for (int i = 0; i < 8; ++i) { b1[i] = ~0ull; b2[i] = ~0ull; }

    // stage one 32-code chunk (hi+lo) with XOR swizzle (slot = c16 ^ (code&15))
    auto stage = [&](int buf, int ch) {
        #pragma unroll
        for (int a = 0; a < 2; ++a) {
            const __bf16* src = a ? el : eh;
            #pragma unroll
            for (int i2 = 0; i2 < 4; ++i2) {
                int s = i2 * 256 + tid;
                int code = s >> 5, c16 = s & 31;
                int gslot = c16 ^ (code & 15);
                const __bf16* gp = src + ((size_t)(ch * 32 + code)) * CDIM + gslot * 8;
                __bf16* ld = ebuf + (size_t)(buf * 2 + a) * 8192 + (size_t)(i2 * 256 + wid * 64) * 8;
                __builtin_amdgcn_global_load_lds((as1cvp)gp, (as3vp)ld, 16, 0, 0);
            }
        }
    };

    stage(0, 0);
    __syncthreads();
    #pragma unroll 2
    for (int ch = 0; ch < 32; ++ch) {
        int cur = ch & 1;
        if (ch < 31) stage(cur ^ 1, ch + 1);

        const __bf16* bh_base = ebuf + (size_t)(cur * 2 + 0) * 8192;
        const __bf16* bl_base = ebuf + (size_t)(cur * 2 + 1) * 8192;

        f32x4 a0[2], a1[2], a2[2];
        #pragma unroll
        for (int mt = 0; mt < 2; ++mt)
            #pragma unroll
            for (int r = 0; r < 4; ++r) { a0[mt][r] = 0.f; a1[mt][r] = 0.f; a2[mt][r] = 0.f; }

        int code_l = nw * 16 + row;
        #pragma unroll
        for (int ks = 0; ks < 8; ++ks) {
            int slot = (ks * 4 + kg) ^ row;
            bf16x8 bh = *reinterpret_cast<const bf16x8*>(bh_base + code_l * 256 + slot * 8);
            bf16x8 bl = *reinterpret_cast<const bf16x8*>(bl_base + code_l * 256 + slot * 8);
            #pragma unroll
            for (int mt = 0; mt < 2; ++mt) {
                a0[mt] = __builtin_amdgcn_mfma_f32_16x16x32_bf16(ah[mt][ks],  bh, a0[mt], 0, 0, 0);
                a1[mt] = __builtin_amdgcn_mfma_f32_16x16x32_bf16(ah[mt][ks],  bl, a1[mt], 0, 0, 0);
                a2[mt] = __builtin_amdgcn_mfma_f32_16x16x32_bf16(al_[mt][ks], bh, a2[mt], 0, 0, 0);
            }
        }

        // selection epilogue: d' = e2 - 2*dot; code col = lane&15
        int code = ch * 32 + code_l;
        float e2v = en2s[code];
        #pragma unroll
        for (int mt = 0; mt < 2; ++mt)
            #pragma unroll
            for (int r = 0; r < 4; ++r) {
                float d = fmaf(-2.0f, (a0[mt][r] + a1[mt][r]) + a2[mt][r], e2v);
                unsigned ub = __float_as_uint(d);
                ub = (ub & 0x80000000u) ? ~ub : (ub | 0x80000000u);
                unsigned long long key = ((unsigned long long)ub << 32) | (unsigned)code;
                int idx = mt * 4 + r;
                if (key < b1[idx]) { b2[idx] = b1[idx]; b1[idx] = key; }
                else if (key < b2[idx]) { b2[idx] = key; }
            }
        __syncthreads();
    }

    // butterfly top-2 merge across the 16 code-col lanes
    #pragma unroll
    for (int i = 0; i < 8; ++i) {
        #pragma unroll
        for (int off = 1; off < 16; off <<= 1) {
            unsigned long long o1 = __shfl_xor(b1[i], off, 16);
            unsigned long long o2 = __shfl_xor(b2[i], off, 16);
            unsigned long long m1 = umin64(b1[i], o1);
            unsigned long long m2 = umin64(umax64(b1[i], o1), umin64(b2[i], o2));
            b1[i] = m1; b2[i] = m2;
        }
    }
    if ((l & 15) == 0) {
        #pragma unroll
        for (int mt = 0; mt < 2; ++mt)
            #pragma unroll
            for (int r = 0; r < 4; ++r) {
                int tl = mw * 32 + mt * 16 + kg * 4 + r;   // C/D row mapping
                t2l[tl][nw][0] = b1[mt * 4 + r];
                t2l[tl][nw][1] = b2[mt * 4 + r];
            }
    }
    __syncthreads();

    // fused fp32 fixup: 4 threads per token, 64 dims each
    {
        int tl = tid >> 2, q = tid & 3;
        int t = t0 + tl;
        unsigned long long x1 = t2l[tl][0][0], x2 = t2l[tl][0][1];
        unsigned long long y1 = t2l[tl][1][0], y2 = t2l[tl][1][1];
        unsigned c1 = (unsigned)umin64(x1, y1);
        unsigned c2 = (unsigned)umin64(umax64(x1, y1), umin64(x2, y2));
        const float4* zp  = reinterpret_cast<const float4*>(znt) + (size_t)t  * C4 + q * 16;
        const float4* eap = reinterpret_cast<const float4*>(en)  + (size_t)c1 * C4 + q * 16;
        const float4* ebp = reinterpret_cast<const float4*>(en)  + (size_t)c2 * C4 + q * 16;
        float da = 0.f, db = 0.f;
        #pragma unroll
        for (int i = 0; i < 16; ++i) {
            float4 zv = zp[i], av = eap[i], bv = ebp[i];
            da += zv.x*av.x + zv.y*av.y + zv.z*av.z + zv.w*av.w;
            db += zv.x*bv.x + zv.y*bv.y + zv.z*bv.z + zv.w*bv.w;
        }
        da += __shfl_xor(da, 1, 4); da += __shfl_xor(da, 2, 4);
        db += __shfl_xor(db, 1, 4); db += __shfl_xor(db, 2, 4);
        if (q == 0) {
            float z2 = znt2[t];
            float d1 = (z2 + en2s[c1]) - 2.0f * da;
            float d2 = (z2 + en2s[c2]) - 2.0f * db;
            int k = (d2 < d1 || (d2 == d1 && c2 < c1)) ? (int)c2 : (int)c1;
            idxs[tl] = k;
            out[(size_t)NTOK * CDIM + t] = (float)k;   // index output tail
        }
    }
    __syncthreads();   // en2s reads done; idxs visible; qt may overwrite

    // gather stage: emb rows -> qt[64][257]; tl varies fastest (bank-safe)
    {
        int tl = tid & 63, q = tid >> 6;       // 4 c-segments of 64 floats
        int kidx = idxs[tl];
        const float4* ep = reinterpret_cast<const float4*>(emb + (size_t)kidx * CDIM + q * 64);
        #pragma unroll
        for (int i = 0; i < 16; ++i) {
            float4 v = ep[i];
            int cb = q * 64 + i * 4;
            qt[tl * 257 + cb + 0] = v.x;
            qt[tl * 257 + cb + 1] = v.y;
            qt[tl * 257 + cb + 2] = v.z;
            qt[tl * 257 + cb + 3] = v.w;
        }
    }
    __syncthreads();

    // transpose write: lanes = hw (coalesced 256B stores), NCHW
    {
        int hwo = tid & 63, cg = tid >> 6;     // 4 c-groups of 64
        int n = t0 >> 10, hw = (t0 & 1023) + hwo;
        float* ob = out + (size_t)n * (CDIM * 1024) + hw;
        #pragma unroll 8
        for (int cc = 0; cc < 64; ++cc) {
            int c = cg * 64 + cc;
            ob[(size_t)c * 1024] = qt[hwo * 257 + c];
        }
    }
}

extern "C" void kernel_launch(void* const* d_in, const int* in_sizes, int n_in,
                              void* d_out, int out_size, void* d_ws, size_t ws_size,
                              hipStream_t stream) {
    const float* z   = (const float*)d_in[0];
    const float* emb = (const float*)d_in[1];
    float* out  = (float*)d_out;

    float*  en   = (float*)d_ws;                        // 1 MB
    float*  en2  = en + (size_t)KCODE * CDIM;           // 4 KB
    float*  znt2 = en2 + KCODE;                         // 128 KB
    __bf16* eh   = (__bf16*)(znt2 + NTOK);              // 512 KB
    __bf16* el   = eh + (size_t)KCODE * CDIM;           // 512 KB
    float*  znt  = (float*)(el + (size_t)KCODE * CDIM); // 32 MB

    k_prep<<<1024 + 16, 256, 0, stream>>>(z, emb, znt, znt2, en, en2, eh, el);
    k_mfma<<<NTOK / 64, 256, 0, stream>>>(znt, eh, el, en2, znt2, en, emb, out);
}